// Round 5
// baseline (30034.714 us; speedup 1.0000x reference)
//
#include <hip/hip_runtime.h>

// NeuralCDE: B=64,T=256,C=16,S=64,H=128. fp32 recursion (f16 decorrelates).
// R17 = R16 with the k-reduction fixed. R16 failed absmax=1.988: after the
// pair-combine shfl_xor(1), BOTH lanes hold the full row f; the channel
// reduce over masks {2,4,8,16} spans only 16 same-parity lanes (each row
// counted ONCE) -> the "*0.5 undo duplication" halved every k. Removed.
// Protocol itself validated by R16: no hang (4-partner co-residency + seq
// exchange ran to completion), finite smooth output (= halved field).
// Design recap: 4 blocks per batch element (grid 256 = CU count). Block p
// owns W2 rows [256p,256p+256): 128KB in LDS, XOR-swizzled ((c4^(rr&31))<<4)
// -> zero per-stage weight traffic (kills the L2 stream that capped R0-R3;
// allocator remat makes >~50 resident floats/thread impossible). k[16]
// exchanged per stage via seq-tagged 8B packets, parity double-buffered,
// agent-scope release/acquire, one-wave vectorized spin. h1/h2 redundant
// per partner (bit-identical -> y coherent).
// SIGNATURE next round: pass, dur 3.0-4.3ms, VALUBusy 15-25%, FETCH ~5.5MB,
// WRITE ~8.3MB, conflicts << 2.5e7. If >=5ms low-conflict: exchange latency
// -> overlap exchange with next h1.

typedef float float4v __attribute__((ext_vector_type(4)));

__device__ __forceinline__ float dot4(float4v a, float4v b) {
  return a.x * b.x + a.y * b.y + a.z * b.z + a.w * b.w;
}

__device__ __forceinline__ float softplus_fast(float x) {
  float z = __expf(-fabsf(x));
  return fmaxf(x, 0.f) + __logf(1.f + z);
}

__device__ __forceinline__ float tanh_hw(float x) {
  float e = __expf(2.f * x);  // inf-safe
  return 1.f - 2.f * __builtin_amdgcn_rcpf(e + 1.f);
}

__global__ __launch_bounds__(512, 2) void cde_main(
    const float* __restrict__ xs,
    const float* __restrict__ icw0, const float* __restrict__ icb0,
    const float* __restrict__ icw1, const float* __restrict__ icb1,
    const float* __restrict__ icw2, const float* __restrict__ icb2,
    const float* __restrict__ vfw0, const float* __restrict__ vfb0,
    const float* __restrict__ vfw1, const float* __restrict__ vfb1,
    const float* __restrict__ vfw2, const float* __restrict__ vfb2,
    unsigned long long* __restrict__ kslab, float* __restrict__ ybuf) {
  constexpr float Ac[6][5] = {
      {0.f, 0.f, 0.f, 0.f, 0.f},
      {0.161f, 0.f, 0.f, 0.f, 0.f},
      {-0.008480655492356989f, 0.335480655492357f, 0.f, 0.f, 0.f},
      {2.8971530571054935f, -6.359448489975075f, 4.3622954328695815f, 0.f, 0.f},
      {5.325864828439257f, -11.748883564062828f, 7.4955393428898365f,
       -0.09249506636175525f, 0.f},
      {5.86145544294642f, -12.92096931784711f, 8.159367898576159f,
       -0.071584973281401f, -0.028269050394068383f}};
  constexpr float SCv[6] = {0.f, 0.161f, 0.327f, 0.9f, 0.9800255409045097f, 1.f};
  constexpr float BWv[6] = {0.09646076681806523f, 0.01f, 0.4798896504144996f,
                            1.379008574103742f, -3.290069515436081f,
                            2.324710524099774f};

  const int tid = threadIdx.x;             // 0..511
  const int w = tid >> 6, l = tid & 63;
  const int b = blockIdx.x & 63;           // batch element
  const int p = blockIdx.x >> 6;           // partner index 0..3 (same-XCD set)

  __shared__ __align__(16) float sW2[32768];    // 128 KB: W2 rows [256p,256p+256)
  __shared__ __align__(16) float sYtw[8][64];   // wave-private stage inputs
  __shared__ __align__(16) float sH1[128];
  __shared__ __align__(16) float sH2[128];
  __shared__ __align__(16) float sK[6][64];

  // ---- one-time: stage this block's 256 W2 rows into LDS, XOR-swizzled.
  // element (rr, c) lives at byte rr*512 + ((c4 ^ (rr&31))<<4) + (c&3)*4,
  // c4 = c>>2. 4-col chunks stay contiguous; 64-lane same-c4 reads are 2-way.
  {
    const float* wsrc = vfw2 + (size_t)p * 32768;
#pragma unroll
    for (int n = 0; n < 16; ++n) {
      int idx4 = tid + n * 512;            // chunk id [0,8192)
      int r_ = idx4 >> 5, c4 = idx4 & 31;
      float4v v = *(const float4v*)(wsrc + (size_t)idx4 * 4);
      *(float4v*)((char*)sW2 + r_ * 512 + ((c4 ^ (r_ & 31)) << 4)) = v;
    }
  }

  // ---- per-thread roles ----
  const int rr = tid >> 1, hh = tid & 1;   // k-phase: row (0..255), col half
  const int ch = rr & 15;                  // dx channel of this row
  const float b2r = vfb2[p * 256 + rr];
  const int ii = tid >> 2, q4 = tid & 3;   // h1/h2: 4 lanes per output
  float w0r[16], w1r[32];
  {
    const float4v* ptr = (const float4v*)(vfw0 + (size_t)ii * 64 + q4 * 16);
#pragma unroll
    for (int kk = 0; kk < 4; ++kk) {
      float4v a = ptr[kk];
      w0r[4 * kk] = a.x; w0r[4 * kk + 1] = a.y;
      w0r[4 * kk + 2] = a.z; w0r[4 * kk + 3] = a.w;
    }
  }
  {
    const float4v* ptr = (const float4v*)(vfw1 + (size_t)ii * 128 + q4 * 32);
#pragma unroll
    for (int kk = 0; kk < 8; ++kk) {
      float4v a = ptr[kk];
      w1r[4 * kk] = a.x; w1r[4 * kk + 1] = a.y;
      w1r[4 * kk + 2] = a.z; w1r[4 * kk + 3] = a.w;
    }
  }
  const float b0i = vfb0[ii], b1i = vfb1[ii];

  const float* Xb = xs + (size_t)b * 4096;
  float* yb = ybuf + (size_t)b * 16384;
  unsigned long long* kb = kslab + (size_t)b * 128;  // [p][parity][16]

  __syncthreads();

  // ---- initial condition MLP (one-time; identical across partners) ----
  float* sTA = &sK[0][0];
  float* sTB = sH1;
  if (tid < 128) {
    float a = icb0[tid];
    const float* wr = icw0 + tid * 16;
#pragma unroll
    for (int k = 0; k < 16; ++k) a += wr[k] * Xb[k];
    sTA[tid] = softplus_fast(a);
  }
  __syncthreads();
  if (tid < 128) {
    float a = icb1[tid];
    const float* wr = icw1 + tid * 128;
    for (int k = 0; k < 128; ++k) a += wr[k] * sTA[k];
    sTB[tid] = softplus_fast(a);
  }
  __syncthreads();
  if (tid < 64) {
    float a = icb2[tid];
    const float* wr = icw2 + tid * 128;
    for (int k = 0; k < 128; ++k) a += wr[k] * sTB[k];
    sH2[tid] = a;  // temp broadcast slot
  }
  __syncthreads();
  float yreg = sH2[l];  // every wave holds y[l]
  if (p == 0 && w == 0) yb[l] = yreg;

  const float hstep = 1.f / 255.f;
  const float invh = 255.f;
  int seq = 0;

#pragma unroll 1
  for (int t = 0; t < 255; ++t) {
    float xt = Xb[t * 16 + ch];
    float xt1 = Xb[(t + 1) * 16 + ch];
    float xtm = (t != 0) ? Xb[(t - 1) * 16 + ch] : xt;
    const float u0 = xt - xt1;                         // (xi - xip1)
    const float dp0 = (xt1 - xt) * invh;               // dfull[t+1]
    const float di0 = (t == 0) ? dp0 : (xt - xtm) * invh;  // dfull[t]
#pragma unroll 1
    for (int j = 0; j < 6; ++j) {
      ++seq;
      // ---- stage input y_j: per-lane, wave-private buffer ----
      {
        float yt = yreg;
#pragma unroll
        for (int m = 0; m < 5; ++m)
          if (m < j) yt += hstep * Ac[j][m] * sK[m][l];
        sYtw[w][l] = yt;
      }
      asm volatile("s_waitcnt lgkmcnt(0)" ::: "memory");  // in-wave only
      // ---- dXdt(sc_j) coefficient for this row's channel ----
      const float sc = SCv[j], s2 = sc * sc;
      const float a1 = (6.f * s2 - 6.f * sc) * invh;
      const float a2 = 3.f * s2 - 4.f * sc + 1.f;
      const float a3 = 3.f * s2 - 2.f * sc;
      const float dxc = a1 * u0 + a2 * di0 + a3 * dp0;
      // ---- h1 = softplus(W0 @ y + b0) ----
      {
        const float4v* yv = (const float4v*)(&sYtw[w][0] + q4 * 16);
        float4v y0 = yv[0], y1 = yv[1], y2 = yv[2], y3 = yv[3];
        float sA = w0r[0] * y0.x + w0r[1] * y0.y + w0r[2] * y0.z +
                   w0r[3] * y0.w + w0r[4] * y1.x + w0r[5] * y1.y +
                   w0r[6] * y1.z + w0r[7] * y1.w;
        float sB = w0r[8] * y2.x + w0r[9] * y2.y + w0r[10] * y2.z +
                   w0r[11] * y2.w + w0r[12] * y3.x + w0r[13] * y3.y +
                   w0r[14] * y3.z + w0r[15] * y3.w;
        float s = sA + sB;
        s += __shfl_xor(s, 1);
        s += __shfl_xor(s, 2);
        if (q4 == 0) sH1[ii] = softplus_fast(s + b0i);
      }
      __syncthreads();
      // ---- h2 = softplus(W1 @ h1 + b1) ----
      {
        const float4v* hv = (const float4v*)(sH1 + q4 * 32);
        float sA = 0.f, sB = 0.f;
#pragma unroll
        for (int kk = 0; kk < 4; ++kk) {
          float4v hA = hv[2 * kk], hB = hv[2 * kk + 1];
          sA += w1r[8 * kk + 0] * hA.x + w1r[8 * kk + 1] * hA.y +
                w1r[8 * kk + 2] * hA.z + w1r[8 * kk + 3] * hA.w;
          sB += w1r[8 * kk + 4] * hB.x + w1r[8 * kk + 5] * hB.y +
                w1r[8 * kk + 6] * hB.z + w1r[8 * kk + 7] * hB.w;
        }
        float s = sA + sB;
        s += __shfl_xor(s, 1);
        s += __shfl_xor(s, 2);
        if (q4 == 0) sH2[ii] = softplus_fast(s + b1i);
      }
      __syncthreads();
      // ---- k: rows 256p..256p+255 of A = tanh(W2 h2 + b2), * dx, c-reduce.
      // 2 threads/row (hh = col half). W from swizzled LDS (2-way, free);
      // h2 chunk is a 2-address broadcast.
      {
        const char* wrow = (const char*)sW2 + rr * 512;
        const int rsw = rr & 31;
        float av0 = 0.f, av1 = 0.f, av2 = 0.f, av3 = 0.f;
#pragma unroll
        for (int q = 0; q < 16; q += 4) {
          int c4 = hh * 16 + q;
          float4v wa = *(const float4v*)(wrow + (((c4 + 0) ^ rsw) << 4));
          float4v wb = *(const float4v*)(wrow + (((c4 + 1) ^ rsw) << 4));
          float4v wc = *(const float4v*)(wrow + (((c4 + 2) ^ rsw) << 4));
          float4v wd = *(const float4v*)(wrow + (((c4 + 3) ^ rsw) << 4));
          float4v ha = *(const float4v*)(sH2 + (c4 + 0) * 4);
          float4v hb = *(const float4v*)(sH2 + (c4 + 1) * 4);
          float4v hc = *(const float4v*)(sH2 + (c4 + 2) * 4);
          float4v hd = *(const float4v*)(sH2 + (c4 + 3) * 4);
          av0 += dot4(wa, ha);
          av1 += dot4(wb, hb);
          av2 += dot4(wc, hc);
          av3 += dot4(wd, hd);
        }
        float acc = (av0 + av1) + (av2 + av3);
        acc += __shfl_xor(acc, 1);               // combine col halves
        float f = tanh_hw(acc + b2r) * dxc;      // both lanes hold full row f
        // channel reduce: masks {2,4,8,16} span 16 same-parity lanes = the
        // 16 rows of this local s, each counted exactly once (NO /2!).
        f += __shfl_xor(f, 2);
        f += __shfl_xor(f, 4);
        f += __shfl_xor(f, 8);
        f += __shfl_xor(f, 16);
        if ((tid & 31) == 0) {                   // one owner per local s
          int sp = tid >> 5;                     // 0..15
          unsigned long long pkt =
              ((unsigned long long)(unsigned)seq << 32) | __float_as_uint(f);
          __hip_atomic_store(kb + ((size_t)p * 2 + (seq & 1)) * 16 + sp, pkt,
                             __ATOMIC_RELEASE, __HIP_MEMORY_SCOPE_AGENT);
          sK[j][p * 16 + sp] = f;
        }
      }
      // ---- gather 48 peer k values (wave 0 only; vectorized spin) ----
      if (w == 0) {
        const int qq = l >> 4, sp = l & 15;
        const int pp = (p + 1 + qq) & 3;
        unsigned long long* src = kb + ((size_t)pp * 2 + (seq & 1)) * 16 + sp;
        bool done = (l >= 48);
        float kv = 0.f;
        while (!__all(done)) {
          if (!done) {
            unsigned long long pkt = __hip_atomic_load(
                src, __ATOMIC_ACQUIRE, __HIP_MEMORY_SCOPE_AGENT);
            if ((unsigned)(pkt >> 32) == (unsigned)seq) {
              kv = __uint_as_float((unsigned)pkt);
              done = true;
            } else {
              __builtin_amdgcn_s_sleep(1);
            }
          }
        }
        if (l < 48) sK[j][pp * 16 + sp] = kv;
      }
      __syncthreads();
    }
    // ---- y_{t+1}: every wave redundantly; partner 0 / wave 0 dumps ----
    {
      float yn = yreg;
#pragma unroll
      for (int m = 0; m < 6; ++m) yn += hstep * BWv[m] * sK[m][l];
      yreg = yn;
      if (p == 0 && w == 0) yb[(size_t)(t + 1) * 64 + l] = yn;
    }
  }
}

// Parallel readout: one thread per (b,t): out6 = y @ ro^T + rob, 6D->SO(3).
__global__ __launch_bounds__(256) void readout(
    const float* __restrict__ ybuf, const float* __restrict__ row,
    const float* __restrict__ rob, float* __restrict__ out) {
  int idx = blockIdx.x * blockDim.x + threadIdx.x;  // b*256+t
  const float* y = ybuf + (size_t)idx * 64;
  float p[6];
#pragma unroll
  for (int o = 0; o < 6; ++o) {
    const float4v* rr = (const float4v*)(row + o * 64);
    const float4v* yv = (const float4v*)y;
    float s = 0.f;
#pragma unroll
    for (int k = 0; k < 16; ++k) s += dot4(rr[k], yv[k]);
    p[o] = s + rob[o];
  }
  float a1x = p[0], a1y = p[1], a1z = p[2];
  float a2x = p[3], a2y = p[4], a2z = p[5];
  float n1 = rsqrtf(a1x * a1x + a1y * a1y + a1z * a1z);
  float b1x = a1x * n1, b1y = a1y * n1, b1z = a1z * n1;
  float d = b1x * a2x + b1y * a2y + b1z * a2z;
  float px = a2x - d * b1x, py = a2y - d * b1y, pz = a2z - d * b1z;
  float n2 = rsqrtf(px * px + py * py + pz * pz);
  float b2x = px * n2, b2y = py * n2, b2z = pz * n2;
  float b3x = b1y * b2z - b1z * b2y;
  float b3y = b1z * b2x - b1x * b2z;
  float b3z = b1x * b2y - b1y * b2x;
  float* o = out + (size_t)idx * 9;
  o[0] = b1x; o[1] = b2x; o[2] = b3x;
  o[3] = b1y; o[4] = b2y; o[5] = b3y;
  o[6] = b1z; o[7] = b2z; o[8] = b3z;
}

extern "C" void kernel_launch(void* const* d_in, const int* in_sizes, int n_in,
                              void* d_out, int out_size, void* d_ws,
                              size_t ws_size, hipStream_t stream) {
  (void)in_sizes; (void)n_in; (void)out_size; (void)ws_size;
  const float* xs   = (const float*)d_in[0];
  const float* icw0 = (const float*)d_in[1];
  const float* icb0 = (const float*)d_in[2];
  const float* icw1 = (const float*)d_in[3];
  const float* icb1 = (const float*)d_in[4];
  const float* icw2 = (const float*)d_in[5];
  const float* icb2 = (const float*)d_in[6];
  const float* vfw0 = (const float*)d_in[7];
  const float* vfb0 = (const float*)d_in[8];
  const float* vfw1 = (const float*)d_in[9];
  const float* vfb1 = (const float*)d_in[10];
  const float* vfw2 = (const float*)d_in[11];
  const float* vfb2 = (const float*)d_in[12];
  const float* row  = (const float*)d_in[13];
  const float* rob  = (const float*)d_in[14];
  float* ybuf = (float*)d_ws;  // 64*256*64 floats = 4 MB
  // k-exchange slab after ybuf: 64 b x 4 p x 2 parity x 16 s x 8 B = 64 KB
  unsigned long long* kslab =
      (unsigned long long*)((char*)d_ws + (4u << 20));

  hipMemsetAsync(kslab, 0, 64 * 128 * 8, stream);  // replay-safe tags
  hipLaunchKernelGGL(cde_main, dim3(256), dim3(512), 0, stream,
                     xs, icw0, icb0, icw1, icb1, icw2, icb2,
                     vfw0, vfb0, vfw1, vfb1, vfw2, vfb2, kslab, ybuf);
  hipLaunchKernelGGL(readout, dim3(64), dim3(256), 0, stream,
                     ybuf, row, rob, (float*)d_out);
}

// Round 6
// 11704.518 us; speedup vs baseline: 2.5661x; 2.5661x over previous
//
#include <hip/hip_runtime.h>

// NeuralCDE: B=64,T=256,C=16,S=64,H=128. fp32 recursion (f16 decorrelates).
// R18: R16/R17 cooperative exchange validated correct but agent-scope spin =
// cross-XCD MALL round-trips (FETCH 70-135MB, WRITE 102MB, 20us/stage,
// 30-70ms variance) -> abandoned. Back to R0 structure (64 blocks, no
// cross-block sync) + the register saga's real fix: plain loads from const
// global are REMATERIALIZABLE defs (R0-R3: allocator reloads at use; "+v"
// asm doesn't help). Inline-asm defs are NOT remat-able -> park W2 cols
// 0..63 (2 rows/thread = 128 floats) in AGPRs via v_accvgpr_write ("=a"),
// read back in the unrolled k-loop via v_accvgpr_read. Unified-file budget
// at wpe(2,2): 128 AGPR + ~75 VGPR base + ~28 transient ~= 230 < 256.
// W2 partition: 64 cols AGPR / 26 streamed (24-float stage-top prefetch +
// 28-float JIT batch, 106KB/stage ~0.7us L2) / 38 LDS. Kills the ~210KB
// remat stream + its k-phase latency exposure.
// SIGNATURE next round: dur 3.8-4.8ms, WRITE ~8.2MB, FETCH ~5.4MB,
// VGPR_Count high (~200+) or VGPR~100+AGPR. If WRITE balloons / dur >=6ms:
// AGPR spill -> cut pins to 96 (48 cols).

typedef float float4v __attribute__((ext_vector_type(4)));
typedef float float2v __attribute__((ext_vector_type(2)));

__device__ __forceinline__ float dot4(float4v a, float4v b) {
  return a.x * b.x + a.y * b.y + a.z * b.z + a.w * b.w;
}

__device__ __forceinline__ float softplus_fast(float x) {
  float z = __expf(-fabsf(x));
  return fmaxf(x, 0.f) + __logf(1.f + z);
}

__device__ __forceinline__ float tanh_hw(float x) {
  float e = __expf(2.f * x);  // inf-safe
  return 1.f - 2.f * __builtin_amdgcn_rcpf(e + 1.f);
}

#define AG_WR(dst, src) \
  asm volatile("v_accvgpr_write_b32 %0, %1" : "=a"(dst) : "v"(src))
#define AG_RD(dst, src) \
  asm volatile("v_accvgpr_read_b32 %0, %1" : "=v"(dst) : "a"(src))

__global__ __attribute__((amdgpu_waves_per_eu(2, 2)))
__launch_bounds__(512, 1) void cde_main(
    const float* __restrict__ xs,
    const float* __restrict__ icw0, const float* __restrict__ icb0,
    const float* __restrict__ icw1, const float* __restrict__ icb1,
    const float* __restrict__ icw2, const float* __restrict__ icb2,
    const float* __restrict__ vfw0, const float* __restrict__ vfb0,
    const float* __restrict__ vfw1, const float* __restrict__ vfb1,
    const float* __restrict__ vfw2, const float* __restrict__ vfb2,
    float* __restrict__ ybuf) {
  constexpr float Ac[6][5] = {
      {0.f, 0.f, 0.f, 0.f, 0.f},
      {0.161f, 0.f, 0.f, 0.f, 0.f},
      {-0.008480655492356989f, 0.335480655492357f, 0.f, 0.f, 0.f},
      {2.8971530571054935f, -6.359448489975075f, 4.3622954328695815f, 0.f, 0.f},
      {5.325864828439257f, -11.748883564062828f, 7.4955393428898365f,
       -0.09249506636175525f, 0.f},
      {5.86145544294642f, -12.92096931784711f, 8.159367898576159f,
       -0.071584973281401f, -0.028269050394068383f}};
  constexpr float SCv[6] = {0.f, 0.161f, 0.327f, 0.9f, 0.9800255409045097f, 1.f};
  constexpr float BWv[6] = {0.09646076681806523f, 0.01f, 0.4798896504144996f,
                            1.379008574103742f, -3.290069515436081f,
                            2.324710524099774f};

  const int tid = threadIdx.x;
  const int w = tid >> 6, l = tid & 63;
  const int b = blockIdx.x;  // one block per batch element

  __shared__ float sW2t[38][1024];              // W2 cols 90..127 col-major
  __shared__ __align__(16) float sYtw[8][64];   // wave-private stage inputs
  __shared__ __align__(16) float sH1[128];
  __shared__ __align__(16) float sH2[128];
  __shared__ float sK[6][64];

  // ---- one-time: LDS W2 tail columns ----
  for (int i = tid; i < 38 * 1024; i += 512) {
    int k = i >> 10, r = i & 1023;
    sW2t[k][r] = vfw2[(size_t)r * 128 + 90 + k];
  }

  // ---- one-time: W2 cols 0..63 of rows r0,r1 -> AGPRs (non-remat defs) ----
  const int r0 = tid * 2, r1 = r0 + 1;
  float agA[64], agB[64];  // AGPR-resident via asm defs; all indices static
  {
    const float4v* p0 = (const float4v*)(vfw2 + (size_t)r0 * 128);
    const float4v* p1 = (const float4v*)(vfw2 + (size_t)r1 * 128);
#pragma unroll
    for (int kk = 0; kk < 16; ++kk) {
      float4v a = p0[kk], c = p1[kk];
      AG_WR(agA[4 * kk + 0], a.x);
      AG_WR(agA[4 * kk + 1], a.y);
      AG_WR(agA[4 * kk + 2], a.z);
      AG_WR(agA[4 * kk + 3], a.w);
      AG_WR(agB[4 * kk + 0], c.x);
      AG_WR(agB[4 * kk + 1], c.y);
      AG_WR(agB[4 * kk + 2], c.z);
      AG_WR(agB[4 * kk + 3], c.w);
    }
  }

  const int ii = tid >> 2, q4 = tid & 3;  // h1/h2: 4 lanes per output
  float w0r[16], w1r[32];
  {
    const float4v* p = (const float4v*)(vfw0 + (size_t)ii * 64 + q4 * 16);
#pragma unroll
    for (int kk = 0; kk < 4; ++kk) {
      float4v a = p[kk];
      w0r[4 * kk] = a.x; w0r[4 * kk + 1] = a.y;
      w0r[4 * kk + 2] = a.z; w0r[4 * kk + 3] = a.w;
    }
  }
  {
    const float4v* p = (const float4v*)(vfw1 + (size_t)ii * 128 + q4 * 32);
#pragma unroll
    for (int kk = 0; kk < 8; ++kk) {
      float4v a = p[kk];
      w1r[4 * kk] = a.x; w1r[4 * kk + 1] = a.y;
      w1r[4 * kk + 2] = a.z; w1r[4 * kk + 3] = a.w;
    }
  }
  // opaque (non-remat) defs for W0/W1 rows: real instruction, asm def
#pragma unroll
  for (int kk = 0; kk < 16; ++kk)
    asm volatile("v_mov_b32 %0, %0" : "+v"(w0r[kk]));
#pragma unroll
  for (int kk = 0; kk < 32; ++kk)
    asm volatile("v_mov_b32 %0, %0" : "+v"(w1r[kk]));

  const float b2r0 = vfb2[r0], b2r1 = vfb2[r1];
  const int c0 = (2 * l) & 15;  // even dx channel of row r0; r1 -> c0+1
  const float b0i = vfb0[ii], b1i = vfb1[ii];

  const float* Xb = xs + (size_t)b * 4096;
  float* yb = ybuf + (size_t)b * 16384;

  __syncthreads();

  // ---- initial condition MLP (one-time; sTA := sK[0..1], sTB := sH1) ----
  float* sTA = &sK[0][0];
  float* sTB = sH1;
  if (tid < 128) {
    float a = icb0[tid];
    const float* wr = icw0 + tid * 16;
#pragma unroll
    for (int k = 0; k < 16; ++k) a += wr[k] * Xb[k];
    sTA[tid] = softplus_fast(a);
  }
  __syncthreads();
  if (tid < 128) {
    float a = icb1[tid];
    const float* wr = icw1 + tid * 128;
    for (int k = 0; k < 128; ++k) a += wr[k] * sTA[k];
    sTB[tid] = softplus_fast(a);
  }
  __syncthreads();
  if (tid < 64) {
    float a = icb2[tid];
    const float* wr = icw2 + tid * 128;
    for (int k = 0; k < 128; ++k) a += wr[k] * sTB[k];
    sH2[tid] = a;  // temp broadcast slot
  }
  __syncthreads();
  float yreg = sH2[l];  // every wave holds y[l]
  if (w == 0) yb[l] = yreg;

  const float hstep = 1.f / 255.f;
  const float invh = 255.f;

#pragma unroll 1
  for (int t = 0; t < 255; ++t) {
    // per-lane x-channel pair (c0, c0+1): j-invariant dXdt basis in regs
    float2v xt = *(const float2v*)(Xb + t * 16 + c0);
    float2v xt1 = *(const float2v*)(Xb + (t + 1) * 16 + c0);
    float2v xtm = xt;
    if (t != 0) xtm = *(const float2v*)(Xb + (t - 1) * 16 + c0);
    const float u0 = xt.x - xt1.x, u1 = xt.y - xt1.y;       // (xi - xip1)
    const float dp0 = (xt1.x - xt.x) * invh;                 // dfull[t+1]
    const float dp1 = (xt1.y - xt.y) * invh;
    float di0 = (t == 0) ? dp0 : (xt.x - xtm.x) * invh;      // dfull[t]
    float di1 = (t == 0) ? dp1 : (xt.y - xtm.y) * invh;
    const float* wr0 = vfw2 + (size_t)r0 * 128;
    const float* wr1 = vfw2 + (size_t)r1 * 128;
#pragma unroll 1
    for (int j = 0; j < 6; ++j) {
      // ---- streamed batch 1: W2 cols 64..75 (prefetched over h1/h2) ----
      float4v sa0 = *(const float4v*)(wr0 + 64);
      float4v sa1 = *(const float4v*)(wr0 + 68);
      float4v sa2 = *(const float4v*)(wr0 + 72);
      float4v sb0 = *(const float4v*)(wr1 + 64);
      float4v sb1 = *(const float4v*)(wr1 + 68);
      float4v sb2 = *(const float4v*)(wr1 + 72);
      // ---- stage input y_j: every wave, per-lane, wave-private buffer ----
      {
        float yt = yreg;
#pragma unroll
        for (int m = 0; m < 5; ++m)
          if (m < j) yt += hstep * Ac[j][m] * sK[m][l];
        sYtw[w][l] = yt;
      }
      asm volatile("s_waitcnt lgkmcnt(0)" ::: "memory");  // in-wave only
      // ---- dXdt(sc_j) in registers ----
      const float sc = SCv[j], s2 = sc * sc;
      const float a1 = (6.f * s2 - 6.f * sc) * invh;
      const float a2 = 3.f * s2 - 4.f * sc + 1.f;
      const float a3 = 3.f * s2 - 2.f * sc;
      const float dx0 = a1 * u0 + a2 * di0 + a3 * dp0;
      const float dx1 = a1 * u1 + a2 * di1 + a3 * dp1;
      // ---- h1 = softplus(W0 @ y + b0) ----
      {
        const float4v* yv = (const float4v*)(&sYtw[w][0] + q4 * 16);
        float4v y0 = yv[0], y1 = yv[1], y2 = yv[2], y3 = yv[3];
        float s = w0r[0] * y0.x + w0r[1] * y0.y + w0r[2] * y0.z +
                  w0r[3] * y0.w + w0r[4] * y1.x + w0r[5] * y1.y +
                  w0r[6] * y1.z + w0r[7] * y1.w + w0r[8] * y2.x +
                  w0r[9] * y2.y + w0r[10] * y2.z + w0r[11] * y2.w +
                  w0r[12] * y3.x + w0r[13] * y3.y + w0r[14] * y3.z +
                  w0r[15] * y3.w;
        s += __shfl_xor(s, 1);
        s += __shfl_xor(s, 2);
        if (q4 == 0) sH1[ii] = softplus_fast(s + b0i);
      }
      __syncthreads();
      // ---- h2 = softplus(W1 @ h1 + b1) ----
      {
        const float4v* hv = (const float4v*)(sH1 + q4 * 32);
        float s = 0.f;
#pragma unroll
        for (int kk = 0; kk < 8; ++kk) {
          float4v h = hv[kk];
          s += w1r[4 * kk] * h.x + w1r[4 * kk + 1] * h.y +
               w1r[4 * kk + 2] * h.z + w1r[4 * kk + 3] * h.w;
        }
        s += __shfl_xor(s, 1);
        s += __shfl_xor(s, 2);
        if (q4 == 0) sH2[ii] = softplus_fast(s + b1i);
      }
      __syncthreads();
      // ---- k: rows r0,r1 of A = tanh(W2 h2 + b2), * dx, reduce over c ----
      {
        const float4v* hv = (const float4v*)sH2;
        float s0 = 0.f, s1 = 0.f;
#pragma unroll
        for (int kk = 0; kk < 16; ++kk) {  // AGPR cols 0..63
          float4v h = hv[kk];
          float a0_, a1_, a2_, a3_, c0_, c1_, c2_, c3_;
          AG_RD(a0_, agA[4 * kk + 0]);
          AG_RD(a1_, agA[4 * kk + 1]);
          AG_RD(a2_, agA[4 * kk + 2]);
          AG_RD(a3_, agA[4 * kk + 3]);
          AG_RD(c0_, agB[4 * kk + 0]);
          AG_RD(c1_, agB[4 * kk + 1]);
          AG_RD(c2_, agB[4 * kk + 2]);
          AG_RD(c3_, agB[4 * kk + 3]);
          s0 += a0_ * h.x + a1_ * h.y + a2_ * h.z + a3_ * h.w;
          s1 += c0_ * h.x + c1_ * h.y + c2_ * h.z + c3_ * h.w;
        }
        {  // streamed batch 1: cols 64..75
          float4v h0 = hv[16], h1 = hv[17], h2f = hv[18];
          s0 += dot4(sa0, h0) + dot4(sa1, h1) + dot4(sa2, h2f);
          s1 += dot4(sb0, h0) + dot4(sb1, h1) + dot4(sb2, h2f);
        }
        {  // streamed batch 2 (JIT): cols 76..89
          float4v ta0 = *(const float4v*)(wr0 + 76);
          float4v ta1 = *(const float4v*)(wr0 + 80);
          float4v ta2 = *(const float4v*)(wr0 + 84);
          float2v ta3 = *(const float2v*)(wr0 + 88);
          float4v tb0 = *(const float4v*)(wr1 + 76);
          float4v tb1 = *(const float4v*)(wr1 + 80);
          float4v tb2 = *(const float4v*)(wr1 + 84);
          float2v tb3 = *(const float2v*)(wr1 + 88);
          float4v h0 = hv[19], h1 = hv[20], h2f = hv[21];
          float2v h3 = *(const float2v*)(sH2 + 88);
          s0 += dot4(ta0, h0) + dot4(ta1, h1) + dot4(ta2, h2f) +
                ta3.x * h3.x + ta3.y * h3.y;
          s1 += dot4(tb0, h0) + dot4(tb1, h1) + dot4(tb2, h2f) +
                tb3.x * h3.x + tb3.y * h3.y;
        }
#pragma unroll 4
        for (int k2 = 0; k2 < 19; ++k2) {  // LDS cols 90..127, pairwise
          float2v hk = *(const float2v*)(sH2 + 90 + 2 * k2);
          float2v wlo = *(const float2v*)&sW2t[2 * k2][r0];
          float2v whi = *(const float2v*)&sW2t[2 * k2 + 1][r0];
          s0 += wlo.x * hk.x + whi.x * hk.y;
          s1 += wlo.y * hk.x + whi.y * hk.y;
        }
        float f = tanh_hw(s0 + b2r0) * dx0 + tanh_hw(s1 + b2r1) * dx1;
        f += __shfl_xor(f, 1);
        f += __shfl_xor(f, 2);
        f += __shfl_xor(f, 4);
        if ((tid & 7) == 0) sK[j][tid >> 3] = f;
      }
      __syncthreads();
    }
    // ---- y_{t+1}: every wave redundantly; wave0 dumps the state ----
    {
      float yn = yreg;
#pragma unroll
      for (int m = 0; m < 6; ++m) yn += hstep * BWv[m] * sK[m][l];
      yreg = yn;
      if (w == 0) yb[(size_t)(t + 1) * 64 + l] = yn;
    }
  }
}

// Parallel readout: one thread per (b,t): out6 = y @ ro^T + rob, 6D->SO(3).
__global__ __launch_bounds__(256) void readout(
    const float* __restrict__ ybuf, const float* __restrict__ row,
    const float* __restrict__ rob, float* __restrict__ out) {
  int idx = blockIdx.x * blockDim.x + threadIdx.x;  // b*256+t
  const float* y = ybuf + (size_t)idx * 64;
  float p[6];
#pragma unroll
  for (int o = 0; o < 6; ++o) {
    const float4v* rr = (const float4v*)(row + o * 64);
    const float4v* yv = (const float4v*)y;
    float s = 0.f;
#pragma unroll
    for (int k = 0; k < 16; ++k) s += dot4(rr[k], yv[k]);
    p[o] = s + rob[o];
  }
  float a1x = p[0], a1y = p[1], a1z = p[2];
  float a2x = p[3], a2y = p[4], a2z = p[5];
  float n1 = rsqrtf(a1x * a1x + a1y * a1y + a1z * a1z);
  float b1x = a1x * n1, b1y = a1y * n1, b1z = a1z * n1;
  float d = b1x * a2x + b1y * a2y + b1z * a2z;
  float px = a2x - d * b1x, py = a2y - d * b1y, pz = a2z - d * b1z;
  float n2 = rsqrtf(px * px + py * py + pz * pz);
  float b2x = px * n2, b2y = py * n2, b2z = pz * n2;
  float b3x = b1y * b2z - b1z * b2y;
  float b3y = b1z * b2x - b1x * b2z;
  float b3z = b1x * b2y - b1y * b2x;
  float* o = out + (size_t)idx * 9;
  o[0] = b1x; o[1] = b2x; o[2] = b3x;
  o[3] = b1y; o[4] = b2y; o[5] = b3y;
  o[6] = b1z; o[7] = b2z; o[8] = b3z;
}

extern "C" void kernel_launch(void* const* d_in, const int* in_sizes, int n_in,
                              void* d_out, int out_size, void* d_ws,
                              size_t ws_size, hipStream_t stream) {
  (void)in_sizes; (void)n_in; (void)out_size; (void)ws_size;
  const float* xs   = (const float*)d_in[0];
  const float* icw0 = (const float*)d_in[1];
  const float* icb0 = (const float*)d_in[2];
  const float* icw1 = (const float*)d_in[3];
  const float* icb1 = (const float*)d_in[4];
  const float* icw2 = (const float*)d_in[5];
  const float* icb2 = (const float*)d_in[6];
  const float* vfw0 = (const float*)d_in[7];
  const float* vfb0 = (const float*)d_in[8];
  const float* vfw1 = (const float*)d_in[9];
  const float* vfb1 = (const float*)d_in[10];
  const float* vfw2 = (const float*)d_in[11];
  const float* vfb2 = (const float*)d_in[12];
  const float* row  = (const float*)d_in[13];
  const float* rob  = (const float*)d_in[14];
  float* ybuf = (float*)d_ws;  // 64*256*64 floats = 4 MB

  hipLaunchKernelGGL(cde_main, dim3(64), dim3(512), 0, stream,
                     xs, icw0, icb0, icw1, icb1, icw2, icb2,
                     vfw0, vfb0, vfw1, vfb1, vfw2, vfb2, ybuf);
  hipLaunchKernelGGL(readout, dim3(64), dim3(256), 0, stream,
                     ybuf, row, rob, (float*)d_out);
}